// Round 1
// 312.924 us; speedup vs baseline: 1.2558x; 1.2558x over previous
//
#include <hip/hip_runtime.h>
#include <hip/hip_bf16.h>
#include <hip/hip_fp16.h>

#define N_NODES 200000
#define N_EDGES 2500000
#define HID 32
#define BN_EPS 1e-5f

#define BKT_SHIFT 10                     // 1024 nodes per bucket
#define B_BKT ((N_NODES + 1023) / 1024)  // 196 buckets
#define PAD 16                           // one counter per 64B line
#define CAPB 14336                       // bucket capacity (mean 12800 + 13.6 sigma)
#define EDGES_PER_BLK 8192
#define NB_SCAT ((N_EDGES + EDGES_PER_BLK - 1) / EDGES_PER_BLK)  // 306

// Stats scratch: 4 contention banks (blockIdx&3), SBANK floats each.
// Within a bank: channel j accumulator at [region + j*16] (64B apart ->
// own TCC line -> atomics parallel across channels).
#define SBANK 4096
#define SSTR 16
#define S1SUM 0
#define S1SQ  16
#define L2SUM 32
#define L2SQ  544
#define L3SUM 1056
#define L3SQ  1568

#define NB1  3125   // gather1: 4 thr/node, 64 nodes/block
#define NBL2 3125   // layer2: 32 nodes/block x ITL2 iters
#define ITL2 2
#define NBH  3125   // gatherH: 64 nodes/block

__device__ __forceinline__ void atomAddF(float* p, float v) {
    unsafeAtomicAdd(p, v);   // native global_atomic_add_f32 on gfx950
}

// K0: zero bucket cursors + banked stats scratch.
__global__ void k_init(int* __restrict__ bcur16, float* __restrict__ stats) {
    int i = blockIdx.x * blockDim.x + threadIdx.x;
    if (i < B_BKT * PAD) bcur16[i] = 0;
    if (i < 4 * SBANK) stats[i] = 0.0f;
}

// S1: scatter edges into capacity-padded buckets (dst>>10), PACKED:
// word = (local_dst<<18) | src   (src < 2^18).
__global__ void __launch_bounds__(1024)
k_scatter(const int* __restrict__ ei, int* __restrict__ bcur16,
          unsigned int* __restrict__ ebuf) {
    __shared__ int lh[B_BKT], lbase[B_BKT], lc[B_BKT];
    int t = threadIdx.x;
    if (t < B_BKT) { lh[t] = 0; lc[t] = 0; }
    __syncthreads();
    int base = blockIdx.x * EDGES_PER_BLK;
    int sv[8], dv[8];
#pragma unroll
    for (int k = 0; k < 8; k++) {
        int e = base + k * 1024 + t;
        if (e < N_EDGES) {
            sv[k] = ei[e];
            dv[k] = ei[N_EDGES + e];
            atomicAdd(&lh[dv[k] >> BKT_SHIFT], 1);
        } else dv[k] = -1;
    }
    __syncthreads();
    if (t < B_BKT) lbase[t] = lh[t] ? atomicAdd(&bcur16[t * PAD], lh[t]) : 0;
    __syncthreads();
#pragma unroll
    for (int k = 0; k < 8; k++) {
        if (dv[k] >= 0) {
            int b = dv[k] >> BKT_SHIFT;
            int loc = atomicAdd(&lc[b], 1);
            ebuf[(size_t)b * CAPB + lbase[b] + loc] =
                ((unsigned)(dv[k] & 1023) << 18) | (unsigned)sv[k];
        }
    }
}

// S2: one block per bucket: degree histogram -> scan -> rowbeg/cnt/norm/xp -> placement.
__global__ void __launch_bounds__(1024)
k_bucket(const unsigned int* __restrict__ ebuf, const int* __restrict__ bcur16,
         const float* __restrict__ x, int* __restrict__ rowbeg,
         int* __restrict__ cntg, float* __restrict__ norm,
         float* __restrict__ xp, int* __restrict__ csrc) {
    __shared__ int hist[1024], rbase[1024];
    __shared__ int wsum[16];
    int b = blockIdx.x;
    int t = threadIdx.x;
    int lane = t & 63, wv = t >> 6;
    int count = bcur16[b * PAD];
    size_t ebase = (size_t)b * CAPB;
    int nbase = b << BKT_SHIFT;
    hist[t] = 0;
    __syncthreads();
    for (int i = t; i < count; i += 1024)
        atomicAdd(&hist[ebuf[ebase + i] >> 18], 1);
    __syncthreads();
    int v = hist[t];
    int val = v;
#pragma unroll
    for (int off = 1; off < 64; off <<= 1) {
        int nn = __shfl_up(val, off);
        if (lane >= off) val += nn;
    }
    if (lane == 63) wsum[wv] = val;
    __syncthreads();
    if (t < 16) {
        int wval = wsum[t];
        int wincl = wval;
#pragma unroll
        for (int off = 1; off < 16; off <<= 1) {
            int nn = __shfl_up(wincl, off, 16);
            if (t >= off) wincl += nn;
        }
        wsum[t] = wincl - wval;   // exclusive wave offset
    }
    __syncthreads();
    int excl = (val - v) + wsum[wv];
    int rb = b * CAPB + excl;
    rbase[t] = rb;
    int n = nbase + t;
    if (n < N_NODES) {
        rowbeg[n] = rb;
        cntg[n] = v;
        float nm = rsqrtf((float)v + 1.0f);
        norm[n] = nm;
        xp[n] = x[n] * nm;
    }
    __syncthreads();
    hist[t] = 0;   // reuse as placement cursors
    __syncthreads();
    for (int i = t; i < count; i += 1024) {
        unsigned int w = ebuf[ebase + i];
        int ld = w >> 18;
        int loc = atomicAdd(&hist[ld], 1);
        csrc[rbase[ld] + loc] = (int)(w & 0x3FFFFu);
    }
}

// K5: layer-1 scalar gather, 4 threads/node (12500 waves -> occupancy cap
// lifted from 38%). Writes sn2[n] = {s_n, norm_n} (8B message table for
// layer 2) + banked block stats.
__global__ void __launch_bounds__(256)
k_gather1(const int* __restrict__ rowbeg, const int* __restrict__ cntg,
          const int* __restrict__ csrc, const float* __restrict__ xp,
          const float* __restrict__ norm, float2* __restrict__ sn2,
          float* __restrict__ stats) {
    __shared__ float ls[256], lq[256];
    int tid = threadIdx.x;
    int nl = tid >> 2, q = tid & 3;
    int n = blockIdx.x * 64 + nl;           // NB1*64 == N_NODES exactly
    int beg = rowbeg[n], dg = cntg[n];
    float A0 = 0.f, A1 = 0.f;
    int i = q;
    for (; i + 4 < dg; i += 8) {
        A0 += xp[csrc[beg + i]];
        A1 += xp[csrc[beg + i + 4]];
    }
    if (i < dg) A0 += xp[csrc[beg + i]];
    float acc = A0 + A1;
    acc += __shfl_xor(acc, 1);
    acc += __shfl_xor(acc, 2);
    float val = 0.f;
    if (q == 0) {
        acc += xp[n];
        float nm = norm[n];
        val = nm * acc;
        sn2[n] = make_float2(val, nm);
    }
    ls[tid] = val; lq[tid] = val * val;
    __syncthreads();
    for (int off = 128; off; off >>= 1) {
        if (tid < (unsigned)off) { ls[tid] += ls[tid + off]; lq[tid] += lq[tid + off]; }
        __syncthreads();
    }
    if (tid == 0) {
        int bo = (blockIdx.x & 3) * SBANK;
        atomAddF(&stats[bo + S1SUM], ls[0]);
        atomAddF(&stats[bo + S1SQ],  lq[0]);
    }
}

// phi contribution of one neighbor p={s,norm} for channel (a,b):
//   norm * relu(a*s + b)
#define PHI(aa, bb, pp) ((pp).y * fmaxf(fmaf((aa), (pp).x, (bb)), 0.f))

// K_L2: replaces fusedA + gatherF. Layer-1 output is a function of the
// SCALAR s_src, so the layer-2 message A32[src][:] is determined by the
// 8B pair sn2[src]={s,norm}. Gather 8B/edge (sn2 is 1.6MB -> L2-resident),
// evaluate relu(a_k*s+b_k) per edge in-register (96 lane-ops/edge), then do
// the 32x32 @W2 matmul ONCE per dst node via conflict-free float4 LDS.
// B[n][j] = norm_n * sum_k W2[k][j] * H_k,
//   H_k = norm_n*y1k(s_n) + sum_src norm_src*y1k(s_src).
__global__ void __launch_bounds__(256)
k_layer2(const int* __restrict__ rowbeg, const int* __restrict__ cntg,
         const int* __restrict__ csrc, const float2* __restrict__ sn2,
         const float* __restrict__ stats, const float* __restrict__ W1,
         const float* __restrict__ g1, const float* __restrict__ be1,
         const float* __restrict__ W2, float* __restrict__ B,
         float* __restrict__ sumO, float* __restrict__ sqO) {
    __shared__ float w2s[1024];
    __shared__ float ajs[32], bjs[32];
    __shared__ float yx[32][36];    // row stride 36: float4-aligned, conflict-free
    __shared__ float red[4][8][8];
    int tid = threadIdx.x;
    for (int i = tid; i < 1024; i += 256) w2s[i] = W2[i];
    if (tid < 32) {
        float sm = stats[S1SUM] + stats[SBANK + S1SUM] +
                   stats[2*SBANK + S1SUM] + stats[3*SBANK + S1SUM];
        float sq = stats[S1SQ] + stats[SBANK + S1SQ] +
                   stats[2*SBANK + S1SQ] + stats[3*SBANK + S1SQ];
        float m   = sm * (1.0f / N_NODES);
        float var = sq * (1.0f / N_NODES) - m * m;
        float w = W1[tid];
        float a = g1[tid] * w * rsqrtf(var * w * w + BN_EPS);
        ajs[tid] = a;
        bjs[tid] = be1[tid] - m * a;
    }
    __syncthreads();
    int nl = tid >> 3, cg = (tid & 7) * 4;   // 8 thr/node, 4 channels each
    float a0 = ajs[cg], a1 = ajs[cg+1], a2 = ajs[cg+2], a3 = ajs[cg+3];
    float b0 = bjs[cg], b1 = bjs[cg+1], b2 = bjs[cg+2], b3 = bjs[cg+3];
    float s0=0,s1=0,s2=0,s3=0,q0=0,q1=0,q2=0,q3=0;
#pragma unroll
    for (int it = 0; it < ITL2; it++) {
        int n = (it * NBL2 + blockIdx.x) * 32 + nl;   // exact cover of N_NODES
        int beg = rowbeg[n], dg = cntg[n];
        float2 self = sn2[n];
        float nm = self.y;
        float h0 = PHI(a0,b0,self), h1 = PHI(a1,b1,self),
              h2 = PHI(a2,b2,self), h3 = PHI(a3,b3,self);
        int i = 0;
        for (; i + 3 < dg; i += 4) {    // 4 independent 8B L2-hit loads in flight
            int e0 = csrc[beg+i],   e1 = csrc[beg+i+1],
                e2 = csrc[beg+i+2], e3 = csrc[beg+i+3];
            float2 p0 = sn2[e0], p1 = sn2[e1], p2 = sn2[e2], p3 = sn2[e3];
            h0 += PHI(a0,b0,p0) + PHI(a0,b0,p1) + PHI(a0,b0,p2) + PHI(a0,b0,p3);
            h1 += PHI(a1,b1,p0) + PHI(a1,b1,p1) + PHI(a1,b1,p2) + PHI(a1,b1,p3);
            h2 += PHI(a2,b2,p0) + PHI(a2,b2,p1) + PHI(a2,b2,p2) + PHI(a2,b2,p3);
            h3 += PHI(a3,b3,p0) + PHI(a3,b3,p1) + PHI(a3,b3,p2) + PHI(a3,b3,p3);
        }
        for (; i < dg; i++) {
            float2 p = sn2[csrc[beg + i]];
            h0 += PHI(a0,b0,p); h1 += PHI(a1,b1,p);
            h2 += PHI(a2,b2,p); h3 += PHI(a3,b3,p);
        }
        __syncthreads();                       // protect prev iter's yx reads
        *(float4*)&yx[nl][cg] = make_float4(h0,h1,h2,h3);
        __syncthreads();
        float o0=0,o1=0,o2=0,o3=0;
#pragma unroll
        for (int k = 0; k < 32; k += 4) {
            float4 hh  = *(const float4*)&yx[nl][k];
            float4 wr0 = *(const float4*)&w2s[(k+0)*32 + cg];
            float4 wr1 = *(const float4*)&w2s[(k+1)*32 + cg];
            float4 wr2 = *(const float4*)&w2s[(k+2)*32 + cg];
            float4 wr3 = *(const float4*)&w2s[(k+3)*32 + cg];
            o0 = fmaf(hh.x,wr0.x, fmaf(hh.y,wr1.x, fmaf(hh.z,wr2.x, fmaf(hh.w,wr3.x, o0))));
            o1 = fmaf(hh.x,wr0.y, fmaf(hh.y,wr1.y, fmaf(hh.z,wr2.y, fmaf(hh.w,wr3.y, o1))));
            o2 = fmaf(hh.x,wr0.z, fmaf(hh.y,wr1.z, fmaf(hh.z,wr2.z, fmaf(hh.w,wr3.z, o2))));
            o3 = fmaf(hh.x,wr0.w, fmaf(hh.y,wr1.w, fmaf(hh.z,wr2.w, fmaf(hh.w,wr3.w, o3))));
        }
        o0 *= nm; o1 *= nm; o2 *= nm; o3 *= nm;
        *(float4*)(B + (size_t)n * 32 + cg) = make_float4(o0,o1,o2,o3);
        s0 += o0; s1 += o1; s2 += o2; s3 += o3;
        q0 += o0*o0; q1 += o1*o1; q2 += o2*o2; q3 += o3*o3;
    }
    // reduce across the 8 node-lanes within each wave (lane bits 3..5)
#pragma unroll
    for (int mask = 32; mask >= 8; mask >>= 1) {
        s0 += __shfl_xor(s0, mask); s1 += __shfl_xor(s1, mask);
        s2 += __shfl_xor(s2, mask); s3 += __shfl_xor(s3, mask);
        q0 += __shfl_xor(q0, mask); q1 += __shfl_xor(q1, mask);
        q2 += __shfl_xor(q2, mask); q3 += __shfl_xor(q3, mask);
    }
    int wv = tid >> 6, ln = tid & 63;
    if (ln < 8) {
        float* r = red[wv][ln];
        r[0]=s0; r[1]=s1; r[2]=s2; r[3]=s3;
        r[4]=q0; r[5]=q1; r[6]=q2; r[7]=q3;
    }
    __syncthreads();
    if (tid < 8) {
        float tacc[8] = {0,0,0,0,0,0,0,0};
#pragma unroll
        for (int w = 0; w < 4; w++)
#pragma unroll
            for (int k = 0; k < 8; k++) tacc[k] += red[w][tid][k];
        int cb = tid * 4;
        int bo = (blockIdx.x & 3) * SBANK;
#pragma unroll
        for (int k = 0; k < 4; k++) {
            atomAddF(&sumO[bo + (cb + k) * SSTR], tacc[k]);
            atomAddF(&sqO [bo + (cb + k) * SSTR], tacc[4 + k]);
        }
    }
}

// K10: fused BN+ReLU + y@W3, pre-scaled by norm[n]. 32 nodes/block, 8 thr/node,
// float4 LDS matmul (same scheme as k_layer2). Writes A16 f16.
__global__ void __launch_bounds__(256)
k_fusedB(const float* __restrict__ norm, const float* __restrict__ sum,
         const float* __restrict__ sumsq, const float* __restrict__ g,
         const float* __restrict__ be, const float* __restrict__ W,
         const float* __restrict__ aggIn, __half* __restrict__ hOut) {
    __shared__ float wl[1024];
    __shared__ float scs[32], shs[32];
    __shared__ float yx[32][36];
    int tid = threadIdx.x;
    for (int i = tid; i < 1024; i += 256) wl[i] = W[i];
    if (tid < 32) {
        int o = tid * SSTR;
        float sm = sum[o] + sum[o+SBANK] + sum[o+2*SBANK] + sum[o+3*SBANK];
        float sq = sumsq[o] + sumsq[o+SBANK] + sumsq[o+2*SBANK] + sumsq[o+3*SBANK];
        float m   = sm * (1.0f / N_NODES);
        float var = sq * (1.0f / N_NODES) - m * m;
        float scj = g[tid] * rsqrtf(var + BN_EPS);
        scs[tid] = scj;
        shs[tid] = be[tid] - m * scj;
    }
    __syncthreads();
    int nl = tid >> 3, cg = (tid & 7) * 4;
    int n = blockIdx.x * 32 + nl;            // 6250*32 == N_NODES exactly
    float4 bi = *(const float4*)(aggIn + (size_t)n * 32 + cg);
    float y0 = fmaxf(scs[cg  ]*bi.x + shs[cg  ], 0.f);
    float y1 = fmaxf(scs[cg+1]*bi.y + shs[cg+1], 0.f);
    float y2 = fmaxf(scs[cg+2]*bi.z + shs[cg+2], 0.f);
    float y3 = fmaxf(scs[cg+3]*bi.w + shs[cg+3], 0.f);
    *(float4*)&yx[nl][cg] = make_float4(y0,y1,y2,y3);
    __syncthreads();
    float o0=0,o1=0,o2=0,o3=0;
#pragma unroll
    for (int k = 0; k < 32; k += 4) {
        float4 hh  = *(const float4*)&yx[nl][k];
        float4 wr0 = *(const float4*)&wl[(k+0)*32 + cg];
        float4 wr1 = *(const float4*)&wl[(k+1)*32 + cg];
        float4 wr2 = *(const float4*)&wl[(k+2)*32 + cg];
        float4 wr3 = *(const float4*)&wl[(k+3)*32 + cg];
        o0 = fmaf(hh.x,wr0.x, fmaf(hh.y,wr1.x, fmaf(hh.z,wr2.x, fmaf(hh.w,wr3.x, o0))));
        o1 = fmaf(hh.x,wr0.y, fmaf(hh.y,wr1.y, fmaf(hh.z,wr2.y, fmaf(hh.w,wr3.y, o1))));
        o2 = fmaf(hh.x,wr0.z, fmaf(hh.y,wr1.z, fmaf(hh.z,wr2.z, fmaf(hh.w,wr3.z, o2))));
        o3 = fmaf(hh.x,wr0.w, fmaf(hh.y,wr1.w, fmaf(hh.z,wr2.w, fmaf(hh.w,wr3.w, o3))));
    }
    float nm = norm[n];
    __half2 ha = __floats2half2_rn(o0 * nm, o1 * nm);
    __half2 hb = __floats2half2_rn(o2 * nm, o3 * nm);
    float2 pk;
    ((__half2*)&pk)[0] = ha;
    ((__half2*)&pk)[1] = hb;
    *(float2*)(hOut + (size_t)n * 32 + cg) = pk;    // one 8B store
}

__device__ __forceinline__ void load8h(const __half* p, float2& f0, float2& f1,
                                       float2& f2, float2& f3) {
    float4 raw = *(const float4*)p;              // one 16B load
    const __half2* h = (const __half2*)&raw;
    f0 = __half22float2(h[0]);
    f1 = __half22float2(h[1]);
    f2 = __half22float2(h[2]);
    f3 = __half22float2(h[3]);
}

// K8b: CSR gather-aggregate, f16 messages. 3125 blocks (12500 waves — the
// old 625-block grid capped occupancy at 30%). Banked stats atomics.
__global__ void __launch_bounds__(256)
k_gatherH(const int* __restrict__ rowbeg, const int* __restrict__ cntg,
          const int* __restrict__ csrc, const __half* __restrict__ A,
          const float* __restrict__ norm, float* __restrict__ B,
          float* __restrict__ sum, float* __restrict__ sumsq) {
    int tid = threadIdx.x;
    int nl = tid >> 2;            // 0..63 node lane
    int c8 = (tid & 3) * 8;       // 8 channels per thread
    int n = blockIdx.x * 64 + nl;  // NBH*64 == N_NODES exactly
    int beg = rowbeg[n], dg = cntg[n];
    float2 a0, a1, a2, a3;
    load8h(A + (size_t)n * 32 + c8, a0, a1, a2, a3);   // self-loop
    int i = 0;
    for (; i + 1 < dg; i += 2) {
        int e0 = csrc[beg + i], e1 = csrc[beg + i + 1];
        float2 b0, b1, b2, b3, c0, c1, c2, c3;
        load8h(A + (size_t)e0 * 32 + c8, b0, b1, b2, b3);
        load8h(A + (size_t)e1 * 32 + c8, c0, c1, c2, c3);
        a0.x += b0.x + c0.x; a0.y += b0.y + c0.y;
        a1.x += b1.x + c1.x; a1.y += b1.y + c1.y;
        a2.x += b2.x + c2.x; a2.y += b2.y + c2.y;
        a3.x += b3.x + c3.x; a3.y += b3.y + c3.y;
    }
    if (i < dg) {
        float2 b0, b1, b2, b3;
        load8h(A + (size_t)csrc[beg + i] * 32 + c8, b0, b1, b2, b3);
        a0.x += b0.x; a0.y += b0.y; a1.x += b1.x; a1.y += b1.y;
        a2.x += b2.x; a2.y += b2.y; a3.x += b3.x; a3.y += b3.y;
    }
    float nm = norm[n];
    float o[8] = {a0.x * nm, a0.y * nm, a1.x * nm, a1.y * nm,
                  a2.x * nm, a2.y * nm, a3.x * nm, a3.y * nm};
    *(float4*)(B + (size_t)n * 32 + c8)     = make_float4(o[0], o[1], o[2], o[3]);
    *(float4*)(B + (size_t)n * 32 + c8 + 4) = make_float4(o[4], o[5], o[6], o[7]);
    float st[16];
#pragma unroll
    for (int k = 0; k < 8; k++) { st[k] = o[k]; st[8 + k] = o[k] * o[k]; }
    // reduce across the 16 node-lanes within each wave (lane bits 2..5)
#pragma unroll
    for (int mask = 32; mask >= 4; mask >>= 1)
#pragma unroll
        for (int k = 0; k < 16; k++) st[k] += __shfl_xor(st[k], mask);
    __shared__ float red[4][4][16];   // [wave][cg][16 stats]
    int wv = tid >> 6, ln = tid & 63;
    if (ln < 4) {
#pragma unroll
        for (int k = 0; k < 16; k++) red[wv][ln][k] = st[k];
    }
    __syncthreads();
    if (tid < 4) {
        float tacc[16];
#pragma unroll
        for (int k = 0; k < 16; k++) tacc[k] = 0.f;
#pragma unroll
        for (int w = 0; w < 4; w++)
#pragma unroll
            for (int k = 0; k < 16; k++) tacc[k] += red[w][tid][k];
        int cb = tid * 8;
        int bo = (blockIdx.x & 3) * SBANK;
#pragma unroll
        for (int k = 0; k < 8; k++) {
            atomAddF(&sum[bo + (cb + k) * SSTR], tacc[k]);
            atomAddF(&sumsq[bo + (cb + k) * SSTR], tacc[8 + k]);
        }
    }
}

// K11: final BN+ReLU + dot with fcW + fcb. 8 thr/node, float4 loads,
// 3-step shfl reduce within the 8-lane channel group.
__global__ void __launch_bounds__(256)
k_final(const float* __restrict__ aggIn, const float* __restrict__ sum,
        const float* __restrict__ sumsq, const float* __restrict__ g,
        const float* __restrict__ be, const float* __restrict__ fcW,
        const float* __restrict__ fcb, float* __restrict__ out) {
    __shared__ float scs[32], shs[32], fws[32];
    int tid = threadIdx.x;
    if (tid < 32) {
        int o = tid * SSTR;
        float sm = sum[o] + sum[o+SBANK] + sum[o+2*SBANK] + sum[o+3*SBANK];
        float sq = sumsq[o] + sumsq[o+SBANK] + sumsq[o+2*SBANK] + sumsq[o+3*SBANK];
        float m   = sm * (1.0f / N_NODES);
        float var = sq * (1.0f / N_NODES) - m * m;
        float scj = g[tid] * rsqrtf(var + BN_EPS);
        scs[tid] = scj;
        shs[tid] = be[tid] - m * scj;
        fws[tid] = fcW[tid];
    }
    __syncthreads();
    int nl = tid >> 3, cg = (tid & 7) * 4;
    int n = blockIdx.x * 32 + nl;            // 6250*32 == N_NODES exactly
    float4 bi = *(const float4*)(aggIn + (size_t)n * 32 + cg);
    float v = fmaxf(scs[cg  ]*bi.x + shs[cg  ], 0.f) * fws[cg  ]
            + fmaxf(scs[cg+1]*bi.y + shs[cg+1], 0.f) * fws[cg+1]
            + fmaxf(scs[cg+2]*bi.z + shs[cg+2], 0.f) * fws[cg+2]
            + fmaxf(scs[cg+3]*bi.w + shs[cg+3], 0.f) * fws[cg+3];
    v += __shfl_xor(v, 1);
    v += __shfl_xor(v, 2);
    v += __shfl_xor(v, 4);
    if ((tid & 7) == 0) out[n] = v + fcb[0];
}

extern "C" void kernel_launch(void* const* d_in, const int* in_sizes, int n_in,
                              void* d_out, int out_size, void* d_ws, size_t ws_size,
                              hipStream_t stream) {
    const float* x   = (const float*)d_in[0];
    const int*   ei  = (const int*)d_in[1];
    // d_in[2] edge_attr: unused by the reference
    const float* W1  = (const float*)d_in[3];
    // b1/b2/b3 cancel under training-mode BN
    const float* g1  = (const float*)d_in[5];
    const float* be1 = (const float*)d_in[6];
    const float* W2  = (const float*)d_in[7];
    const float* g2  = (const float*)d_in[9];
    const float* be2 = (const float*)d_in[10];
    const float* W3  = (const float*)d_in[11];
    const float* g3  = (const float*)d_in[13];
    const float* be3 = (const float*)d_in[14];
    const float* fcW = (const float*)d_in[15];
    const float* fcb = (const float*)d_in[16];
    float* out = (float*)d_out;

    // Workspace. Region0 [0, 12.8M) time-multiplexed (strictly ordered):
    //   ebuf u32[196*14336] = 11.2MB (last read k_bucket)
    //   A16 f16  N*32 = 12.8MB (k_fusedB -> k_gatherH)
    char* base = (char*)d_ws;
    __half*       A16  = (__half*)base;
    unsigned int* ebuf = (unsigned int*)base;
    float*  B      = (float*)(base + (size_t)N_NODES * 32 * 4);   // 25.6MB
    int*    csrc   = (int*)(base + (size_t)N_NODES * 32 * 8);     // 11.2MB
    int*    rowbeg = csrc + (size_t)B_BKT * CAPB;
    int*    cntg   = rowbeg + N_NODES;
    float*  norm   = (float*)(cntg + N_NODES);
    float*  xp     = norm + N_NODES;
    float2* sn2    = (float2*)(xp + N_NODES);       // {s_n, norm_n}, 1.6MB
    float*  stats  = (float*)(sn2 + N_NODES);       // 4 banks x 4096 floats
    int*    bcur16 = (int*)(stats + 4 * SBANK);     // [B_BKT*16]

    k_init   <<<64, 256, 0, stream>>>(bcur16, stats);
    k_scatter<<<NB_SCAT, 1024, 0, stream>>>(ei, bcur16, ebuf);
    k_bucket <<<B_BKT, 1024, 0, stream>>>(ebuf, bcur16, x, rowbeg, cntg, norm, xp, csrc);
    k_gather1<<<NB1, 256, 0, stream>>>(rowbeg, cntg, csrc, xp, norm, sn2, stats);
    k_layer2 <<<NBL2, 256, 0, stream>>>(rowbeg, cntg, csrc, sn2, stats,
                                        W1, g1, be1, W2, B,
                                        stats + L2SUM, stats + L2SQ);
    k_fusedB <<<6250, 256, 0, stream>>>(norm, stats + L2SUM, stats + L2SQ,
                                        g2, be2, W3, B, A16);
    k_gatherH<<<NBH, 256, 0, stream>>>(rowbeg, cntg, csrc, A16, norm, B,
                                       stats + L3SUM, stats + L3SQ);
    k_final  <<<6250, 256, 0, stream>>>(B, stats + L3SUM, stats + L3SQ,
                                        g3, be3, fcW, fcb, out);
}